// Round 19
// baseline (96.984 us; speedup 1.0000x reference)
//
#include <hip/hip_runtime.h>

// Problem constants (fixed by the reference setup)
#define BB 2
#define NN 4096
#define EE 65536
#define MM 4
#define HH 256
#define NPB 16     // nodes per block
#define NXCD 8
#define XPAD 264   // xs row stride in fp16 (528B)

typedef float vf4 __attribute__((ext_vector_type(4)));
typedef int vi2 __attribute__((ext_vector_type(2)));
typedef _Float16 vh4 __attribute__((ext_vector_type(4)));
typedef _Float16 f16x8 __attribute__((ext_vector_type(8)));
typedef float f32x4 __attribute__((ext_vector_type(4)));

// ---------------------------------------------------------------------------
// k_prep (grid-partitioned; overlaps three independent HBM streams):
//  part A [0, 8192): per-edge coeff + packed (src,coeff) build, 4 edges/wave.
//          NO cnt reset needed: each call adds exactly 16 per node, so
//          atomicAdd(cnt)&15 yields 16 distinct slots per call from ANY start;
//          list permutation varies but max is permutation-invariant.
//  part B [8192, 16384): hint f32 -> fp16, XCD-ALIGNED: part-B block j
//          (XCD j%8) converts 4 rows of slice (b,m)=j&7 — the same unit->XCD
//          mapping k_fused reads with. ONE float4 per thread:
//          4 rows x 64 float4 = 256 threads exactly (r18 bug: a leftover q-loop
//          wrote 16 rows per block -> 4x overlap + OOB past h16 -> core dump).
//  part C [16384, 16448): W -> Wt fp16 transpose (verified r13)
// ---------------------------------------------------------------------------
#define PREP_A 8192
#define PREP_B 8192
#define PREP_C 64

__global__ __launch_bounds__(256) void k_prep(const float* __restrict__ edge_fts,
                                              const float* __restrict__ edge_W,
                                              const float* __restrict__ edge_b,
                                              const int* __restrict__ cfg,
                                              unsigned int* __restrict__ cnt,
                                              int2* __restrict__ packed,
                                              const float* __restrict__ hint,
                                              _Float16* __restrict__ h16,
                                              const float* __restrict__ W,
                                              _Float16* __restrict__ wt_hi) {
  const int blk = blockIdx.x;
  const int t = threadIdx.x;
  if (blk < PREP_A) {
    // ---- part A: coeff + build, 4 edges per wave ----
    const int e0 = blk * 16 + (t >> 6) * 4;   // first of 4 flat edge indices
    const int lane = t & 63;
    const float4 wv = *reinterpret_cast<const float4*>(edge_W + lane * 4);
    vf4 ef[4];
#pragma unroll
    for (int q = 0; q < 4; ++q)
      ef[q] = __builtin_nontemporal_load(
          reinterpret_cast<const vf4*>(edge_fts + (size_t)(e0 + q) * HH + lane * 4));
    float s[4];
#pragma unroll
    for (int q = 0; q < 4; ++q)
      s[q] = ef[q].x * wv.x + ef[q].y * wv.y + ef[q].z * wv.z + ef[q].w * wv.w;
#pragma unroll
    for (int off = 32; off > 0; off >>= 1) {
#pragma unroll
      for (int q = 0; q < 4; ++q) s[q] += __shfl_down(s[q], off);
    }
    if (lane == 0) {
      const float eb = edge_b[0];
#pragma unroll
      for (int q = 0; q < 4; ++q) {
        const int widx = e0 + q;
        const int b = widx >> 16;  // E = 65536
        const vi2 st = __builtin_nontemporal_load(
            reinterpret_cast<const vi2*>(cfg + (size_t)widx * 2));  // (src, tgt)
        const int slot = b * NN + st.y;
        const unsigned p = atomicAdd(&cnt[slot], 1u) & 15u;  // 16 adds/call -> distinct
        int2 v;
        v.x = st.x;
        v.y = __float_as_int(s[q] + eb);
        packed[(size_t)slot * 16 + p] = v;
      }
    }
  } else if (blk < PREP_A + PREP_B) {
    // ---- part B: hint -> fp16, XCD-aligned; ONE float4 per thread ----
    const int j = blk - PREP_A;            // 0..8191; XCD = blk%8 = j%8
    const int unit = j & 7;                // slice (b,m) this XCD owns in k_fused
    const int g = j >> 3;                  // 0..1023: row group (4 rows)
    const int b = unit >> 2;
    const int m = unit & 3;
    const int row = g * 4 + (t >> 6);      // 0..4095
    const int c4 = t & 63;
    const size_t off = (((size_t)(b * NN + row) * MM + m) * HH) + c4 * 4;
    const vf4 v = __builtin_nontemporal_load(
        reinterpret_cast<const vf4*>(hint + off));
    vh4 h;
    h.x = (_Float16)v.x; h.y = (_Float16)v.y;
    h.z = (_Float16)v.z; h.w = (_Float16)v.w;
    *reinterpret_cast<vh4*>(h16 + off) = h;
  } else {
    // ---- part C: Wt transpose (fp16) ----
    const int jb = blk - PREP_A - PREP_B;   // 0..63
    const int j = jb * 4 + (t >> 6);        // output row of Wt = column of W
    const int h0 = (t & 63) * 4;
    vh4 hi;
    hi.x = (_Float16)W[(size_t)(h0 + 0) * HH + j];
    hi.y = (_Float16)W[(size_t)(h0 + 1) * HH + j];
    hi.z = (_Float16)W[(size_t)(h0 + 2) * HH + j];
    hi.w = (_Float16)W[(size_t)(h0 + 3) * HH + j];
    *reinterpret_cast<vh4*>(wt_hi + (size_t)j * HH + h0) = hi;
  }
}

__device__ __forceinline__ float4 fmax4(const float4& a, const float4& b) {
  return make_float4(fmaxf(a.x, b.x), fmaxf(a.y, b.y), fmaxf(a.z, b.z), fmaxf(a.w, b.w));
}

__device__ __forceinline__ float4 scmul(float c, const vh4& h) {
  return make_float4(c * (float)h.x, c * (float)h.y, c * (float)h.z, c * (float)h.w);
}

// ---------------------------------------------------------------------------
// k_fused (XCD-sharded, fp16 gather + MFMA GEMM) — r15 body, launch_bounds
// (256,6): r15's (256,8) capped VGPR at 64 < stage-1 live set (~80) -> likely
// spilled. 6 waves/SIMD cap -> ~85 VGPR, 6 blocks/CU.
//   stage 0 (intra-wave): thread t stages (row t>>4, slot t&15); no barrier.
//   stage 1: per row: 16 independent 512B half4 loads, scale, tree-max,
//            + node_fts(NT) -> fp16 -> xs[row]
//   stage 2 (after single barrier): wave w: col-tiles w*4..+3, rows 0..15.
//           A[row=l&15][k=(l>>4)*8+..], B[k][col=l&15], D[row=(l>>4)*4+r][col]
//           (layout validated r11).
// ---------------------------------------------------------------------------
__global__ __launch_bounds__(256, 6) void k_fused(const _Float16* __restrict__ h16,
                                                  const float* __restrict__ node_fts,
                                                  const int2* __restrict__ packed,
                                                  const _Float16* __restrict__ wt_hi,
                                                  const float* __restrict__ bias,
                                                  float* __restrict__ out) {
  __shared__ _Float16 xs[NPB][XPAD];   // 8.4 KB
  __shared__ int ssrc[NPB][16];        // 1 KB
  __shared__ float scf[NPB][16];       // 1 KB

  const int t = threadIdx.x;
  const int unit = blockIdx.x & (NXCD - 1);   // = b*4 + m  (XCD-pinned slice)
  const int chunk = blockIdx.x >> 3;
  const int b = unit >> 2;
  const int m = unit & 3;
  const int n0 = chunk * NPB;
  const int w = t >> 6;
  const int lane = t & 63;
  const int r0 = w * 4;     // this wave's first local row

  // ---- stage 0 (intra-wave): thread t stages (row t>>4, slot t&15) ----
  {
    const int i = t >> 4, k = t & 15;   // i in [4w, 4w+3] for this wave
    const int2 v = packed[(size_t)(b * NN + n0 + i) * 16 + k];
    ssrc[i][k] = v.x;
    scf[i][k] = __int_as_float(v.y);
  }

  // per-thread base into h16 for (b, m, lane)
  const _Float16* hb = h16 + (size_t)b * NN * MM * HH + m * HH + lane * 4;

  // ---- stage 1: fp16 gather + scale + tree-max + node_fts -> xs (own rows) ----
#pragma unroll 1
  for (int i = 0; i < 4; ++i) {
    const int lr = r0 + i;
    const int n = n0 + lr;
    vh4 hv[16];
#pragma unroll
    for (int k = 0; k < 16; ++k) {
      const int s = ssrc[lr][k];
      hv[k] = *reinterpret_cast<const vh4*>(hb + (size_t)s * (MM * HH));
    }
    float4 t8[8];
#pragma unroll
    for (int k = 0; k < 8; ++k)
      t8[k] = fmax4(scmul(scf[lr][2 * k], hv[2 * k]),
                    scmul(scf[lr][2 * k + 1], hv[2 * k + 1]));
#pragma unroll
    for (int k = 0; k < 4; ++k) t8[k] = fmax4(t8[k], t8[k + 4]);
    t8[0] = fmax4(t8[0], t8[2]);
    t8[1] = fmax4(t8[1], t8[3]);
    const float4 a = fmax4(t8[0], t8[1]);
    const vf4 nf = __builtin_nontemporal_load(reinterpret_cast<const vf4*>(
        node_fts + (((size_t)(b * NN + n) * MM + m) * HH) + lane * 4));
    vh4 xq;
    xq.x = (_Float16)(nf.x + a.x);
    xq.y = (_Float16)(nf.y + a.y);
    xq.z = (_Float16)(nf.z + a.z);
    xq.w = (_Float16)(nf.w + a.w);
    *reinterpret_cast<vh4*>(&xs[lr][lane * 4]) = xq;
  }
  __syncthreads();  // stage 2 reads rows produced by all waves

  // ---- stage 2: MFMA GEMM [16x256] = xs[16x256] @ W[256x256] ----
  const int lr16 = lane & 15;
  const int kg = lane >> 4;         // 0..3: k-subgroup (8 consecutive k)

#pragma unroll 1
  for (int ct = 0; ct < 4; ++ct) {
    const int j = (w * 4 + ct) * 16 + lr16;
    const _Float16* bh = wt_hi + (size_t)j * HH + kg * 8;
    f32x4 acc = {0.f, 0.f, 0.f, 0.f};
#pragma unroll
    for (int kt = 0; kt < 8; ++kt) {
      const f16x8 bhi = *reinterpret_cast<const f16x8*>(bh + kt * 32);
      const f16x8 a = *reinterpret_cast<const f16x8*>(&xs[lr16][kt * 32 + kg * 8]);
      acc = __builtin_amdgcn_mfma_f32_16x16x32_f16(a, bhi, acc, 0, 0, 0);
    }
    const float bj = bias[j];
#pragma unroll
    for (int r = 0; r < 4; ++r) {
      const int n = n0 + kg * 4 + r;
      __builtin_nontemporal_store(
          acc[r] + bj, out + (((size_t)(b * NN + n) * MM + m) * HH) + j);
    }
  }
}

// ---------------------------------------------------------------------------
extern "C" void kernel_launch(void* const* d_in, const int* in_sizes, int n_in,
                              void* d_out, int out_size, void* d_ws, size_t ws_size,
                              hipStream_t stream) {
  const int* cfg = (const int*)d_in[0];          // [B,E,2]
  const float* hint = (const float*)d_in[1];     // [B,N,M,H]
  const float* node_fts = (const float*)d_in[2]; // [B,N,M,H]
  const float* edge_fts = (const float*)d_in[3]; // [B,E,H]
  const float* edge_W = (const float*)d_in[4];   // [H,1]
  const float* edge_b = (const float*)d_in[5];   // [1]
  const float* update_W = (const float*)d_in[6]; // [H,H]
  const float* update_b = (const float*)d_in[7]; // [H]
  float* out = (float*)d_out;

  char* ws = (char*)d_ws;
  unsigned int* cnt = (unsigned int*)ws;                         // 32 KB (never reset)
  int2* packed = (int2*)(ws + 32768);                            // B*N*16 int2 = 1 MB
  _Float16* h16 = (_Float16*)(ws + 32768 + 1048576);             // 16.78 MB
  _Float16* wt_hi = (_Float16*)(ws + 32768 + 1048576 + 16777216);  // 128 KB

  // 1) fused prep: coeff+build || hint->fp16 (XCD-aligned) || Wt transpose
  k_prep<<<PREP_A + PREP_B + PREP_C, 256, 0, stream>>>(
      edge_fts, edge_W, edge_b, cfg, cnt, packed, hint, h16, update_W, wt_hi);
  // 2) fused gather-max + MFMA linear update; grid unit-major for XCD sharding
  k_fused<<<BB * MM * (NN / NPB), 256, 0, stream>>>(h16, node_fts, packed,
                                                    wt_hi, update_b, out);
}

// Round 20
// 92.655 us; speedup vs baseline: 1.0467x; 1.0467x over previous
//
#include <hip/hip_runtime.h>

// Problem constants (fixed by the reference setup)
#define BB 2
#define NN 4096
#define EE 65536
#define MM 4
#define HH 256
#define NPB 16     // nodes per block
#define NXCD 8
#define XPAD 264   // xs row stride in fp16 (528B)

typedef float vf4 __attribute__((ext_vector_type(4)));
typedef int vi2 __attribute__((ext_vector_type(2)));
typedef _Float16 vh4 __attribute__((ext_vector_type(4)));
typedef _Float16 f16x8 __attribute__((ext_vector_type(8)));
typedef float f32x4 __attribute__((ext_vector_type(4)));

// ---------------------------------------------------------------------------
// k_prep (grid-partitioned; overlaps three independent HBM streams):
//  part A [0, 4096): per-edge coeff + packed build, 8 edges/wave.
//          r20: butterfly (shfl_xor) reduce -> ALL lanes hold each sum; lanes
//          0..7 then each run one edge's tail (cfg load + atomicAdd + store)
//          IN PARALLEL (was lane-0-serial x4 — a ~500cy dependent chain per
//          edge that dominated prep's ~20us excess over its HBM floor).
//          NO cnt reset needed: exactly 16 adds/node/call -> &15 gives 16
//          distinct slots from any start; max is permutation-invariant.
//  part B [4096, 12288): hint f32 -> fp16, XCD-aligned, one float4/thread.
//  part C [12288, 12352): W -> Wt fp16 transpose (verified r13)
// ---------------------------------------------------------------------------
#define PREP_A 4096
#define PREP_B 8192
#define PREP_C 64

__global__ __launch_bounds__(256) void k_prep(const float* __restrict__ edge_fts,
                                              const float* __restrict__ edge_W,
                                              const float* __restrict__ edge_b,
                                              const int* __restrict__ cfg,
                                              unsigned int* __restrict__ cnt,
                                              int2* __restrict__ packed,
                                              const float* __restrict__ hint,
                                              _Float16* __restrict__ h16,
                                              const float* __restrict__ W,
                                              _Float16* __restrict__ wt_hi) {
  const int blk = blockIdx.x;
  const int t = threadIdx.x;
  if (blk < PREP_A) {
    // ---- part A: coeff + build, 8 edges per wave ----
    const int e0 = blk * 32 + (t >> 6) * 8;   // first of 8 flat edge indices
    const int lane = t & 63;
    const float4 wv = *reinterpret_cast<const float4*>(edge_W + lane * 4);
    vf4 ef[8];
#pragma unroll
    for (int q = 0; q < 8; ++q)
      ef[q] = __builtin_nontemporal_load(
          reinterpret_cast<const vf4*>(edge_fts + (size_t)(e0 + q) * HH + lane * 4));
    float s[8];
#pragma unroll
    for (int q = 0; q < 8; ++q)
      s[q] = ef[q].x * wv.x + ef[q].y * wv.y + ef[q].z * wv.z + ef[q].w * wv.w;
    // butterfly: every lane ends with the full 64-lane sum of each edge
#pragma unroll
    for (int off = 1; off < 64; off <<= 1) {
#pragma unroll
      for (int q = 0; q < 8; ++q) s[q] += __shfl_xor(s[q], off);
    }
    if (lane < 8) {
      // compile-time select chain (no runtime-indexed array -> no scratch)
      const float sv = (lane == 0) ? s[0] : (lane == 1) ? s[1] : (lane == 2) ? s[2]
                     : (lane == 3) ? s[3] : (lane == 4) ? s[4] : (lane == 5) ? s[5]
                     : (lane == 6) ? s[6] : s[7];
      const int widx = e0 + lane;
      const int b = widx >> 16;  // E = 65536
      const vi2 st = __builtin_nontemporal_load(
          reinterpret_cast<const vi2*>(cfg + (size_t)widx * 2));  // (src, tgt)
      const int slot = b * NN + st.y;
      const unsigned p = atomicAdd(&cnt[slot], 1u) & 15u;
      int2 v;
      v.x = st.x;
      v.y = __float_as_int(sv + edge_b[0]);
      packed[(size_t)slot * 16 + p] = v;
    }
  } else if (blk < PREP_A + PREP_B) {
    // ---- part B: hint -> fp16, XCD-aligned; ONE float4 per thread ----
    const int j = blk - PREP_A;            // 0..8191
    const int unit = j & 7;                // slice (b,m) this XCD owns in k_fused
    const int g = j >> 3;                  // 0..1023: row group (4 rows)
    const int b = unit >> 2;
    const int m = unit & 3;
    const int row = g * 4 + (t >> 6);      // 0..4095
    const int c4 = t & 63;
    const size_t off = (((size_t)(b * NN + row) * MM + m) * HH) + c4 * 4;
    const vf4 v = __builtin_nontemporal_load(
        reinterpret_cast<const vf4*>(hint + off));
    vh4 h;
    h.x = (_Float16)v.x; h.y = (_Float16)v.y;
    h.z = (_Float16)v.z; h.w = (_Float16)v.w;
    *reinterpret_cast<vh4*>(h16 + off) = h;
  } else {
    // ---- part C: Wt transpose (fp16) ----
    const int jb = blk - PREP_A - PREP_B;   // 0..63
    const int j = jb * 4 + (t >> 6);        // output row of Wt = column of W
    const int h0 = (t & 63) * 4;
    vh4 hi;
    hi.x = (_Float16)W[(size_t)(h0 + 0) * HH + j];
    hi.y = (_Float16)W[(size_t)(h0 + 1) * HH + j];
    hi.z = (_Float16)W[(size_t)(h0 + 2) * HH + j];
    hi.w = (_Float16)W[(size_t)(h0 + 3) * HH + j];
    *reinterpret_cast<vh4*>(wt_hi + (size_t)j * HH + h0) = hi;
  }
}

__device__ __forceinline__ float4 fmax4(const float4& a, const float4& b) {
  return make_float4(fmaxf(a.x, b.x), fmaxf(a.y, b.y), fmaxf(a.z, b.z), fmaxf(a.w, b.w));
}

__device__ __forceinline__ float4 scmul(float c, const vh4& h) {
  return make_float4(c * (float)h.x, c * (float)h.y, c * (float)h.z, c * (float)h.w);
}

// ---------------------------------------------------------------------------
// k_fused (XCD-sharded, fp16 gather + MFMA GEMM) — unchanged from r19
// (proven: 0.0625 absmax, ~42us est).
// ---------------------------------------------------------------------------
__global__ __launch_bounds__(256, 6) void k_fused(const _Float16* __restrict__ h16,
                                                  const float* __restrict__ node_fts,
                                                  const int2* __restrict__ packed,
                                                  const _Float16* __restrict__ wt_hi,
                                                  const float* __restrict__ bias,
                                                  float* __restrict__ out) {
  __shared__ _Float16 xs[NPB][XPAD];   // 8.4 KB
  __shared__ int ssrc[NPB][16];        // 1 KB
  __shared__ float scf[NPB][16];       // 1 KB

  const int t = threadIdx.x;
  const int unit = blockIdx.x & (NXCD - 1);   // = b*4 + m  (XCD-pinned slice)
  const int chunk = blockIdx.x >> 3;
  const int b = unit >> 2;
  const int m = unit & 3;
  const int n0 = chunk * NPB;
  const int w = t >> 6;
  const int lane = t & 63;
  const int r0 = w * 4;     // this wave's first local row

  // ---- stage 0 (intra-wave): thread t stages (row t>>4, slot t&15) ----
  {
    const int i = t >> 4, k = t & 15;   // i in [4w, 4w+3] for this wave
    const int2 v = packed[(size_t)(b * NN + n0 + i) * 16 + k];
    ssrc[i][k] = v.x;
    scf[i][k] = __int_as_float(v.y);
  }

  // per-thread base into h16 for (b, m, lane)
  const _Float16* hb = h16 + (size_t)b * NN * MM * HH + m * HH + lane * 4;

  // ---- stage 1: fp16 gather + scale + tree-max + node_fts -> xs (own rows) ----
#pragma unroll 1
  for (int i = 0; i < 4; ++i) {
    const int lr = r0 + i;
    const int n = n0 + lr;
    vh4 hv[16];
#pragma unroll
    for (int k = 0; k < 16; ++k) {
      const int s = ssrc[lr][k];
      hv[k] = *reinterpret_cast<const vh4*>(hb + (size_t)s * (MM * HH));
    }
    float4 t8[8];
#pragma unroll
    for (int k = 0; k < 8; ++k)
      t8[k] = fmax4(scmul(scf[lr][2 * k], hv[2 * k]),
                    scmul(scf[lr][2 * k + 1], hv[2 * k + 1]));
#pragma unroll
    for (int k = 0; k < 4; ++k) t8[k] = fmax4(t8[k], t8[k + 4]);
    t8[0] = fmax4(t8[0], t8[2]);
    t8[1] = fmax4(t8[1], t8[3]);
    const float4 a = fmax4(t8[0], t8[1]);
    const vf4 nf = __builtin_nontemporal_load(reinterpret_cast<const vf4*>(
        node_fts + (((size_t)(b * NN + n) * MM + m) * HH) + lane * 4));
    vh4 xq;
    xq.x = (_Float16)(nf.x + a.x);
    xq.y = (_Float16)(nf.y + a.y);
    xq.z = (_Float16)(nf.z + a.z);
    xq.w = (_Float16)(nf.w + a.w);
    *reinterpret_cast<vh4*>(&xs[lr][lane * 4]) = xq;
  }
  __syncthreads();  // stage 2 reads rows produced by all waves

  // ---- stage 2: MFMA GEMM [16x256] = xs[16x256] @ W[256x256] ----
  const int lr16 = lane & 15;
  const int kg = lane >> 4;         // 0..3: k-subgroup (8 consecutive k)

#pragma unroll 1
  for (int ct = 0; ct < 4; ++ct) {
    const int j = (w * 4 + ct) * 16 + lr16;
    const _Float16* bh = wt_hi + (size_t)j * HH + kg * 8;
    f32x4 acc = {0.f, 0.f, 0.f, 0.f};
#pragma unroll
    for (int kt = 0; kt < 8; ++kt) {
      const f16x8 bhi = *reinterpret_cast<const f16x8*>(bh + kt * 32);
      const f16x8 a = *reinterpret_cast<const f16x8*>(&xs[lr16][kt * 32 + kg * 8]);
      acc = __builtin_amdgcn_mfma_f32_16x16x32_f16(a, bhi, acc, 0, 0, 0);
    }
    const float bj = bias[j];
#pragma unroll
    for (int r = 0; r < 4; ++r) {
      const int n = n0 + kg * 4 + r;
      __builtin_nontemporal_store(
          acc[r] + bj, out + (((size_t)(b * NN + n) * MM + m) * HH) + j);
    }
  }
}

// ---------------------------------------------------------------------------
extern "C" void kernel_launch(void* const* d_in, const int* in_sizes, int n_in,
                              void* d_out, int out_size, void* d_ws, size_t ws_size,
                              hipStream_t stream) {
  const int* cfg = (const int*)d_in[0];          // [B,E,2]
  const float* hint = (const float*)d_in[1];     // [B,N,M,H]
  const float* node_fts = (const float*)d_in[2]; // [B,N,M,H]
  const float* edge_fts = (const float*)d_in[3]; // [B,E,H]
  const float* edge_W = (const float*)d_in[4];   // [H,1]
  const float* edge_b = (const float*)d_in[5];   // [1]
  const float* update_W = (const float*)d_in[6]; // [H,H]
  const float* update_b = (const float*)d_in[7]; // [H]
  float* out = (float*)d_out;

  char* ws = (char*)d_ws;
  unsigned int* cnt = (unsigned int*)ws;                         // 32 KB (never reset)
  int2* packed = (int2*)(ws + 32768);                            // B*N*16 int2 = 1 MB
  _Float16* h16 = (_Float16*)(ws + 32768 + 1048576);             // 16.78 MB
  _Float16* wt_hi = (_Float16*)(ws + 32768 + 1048576 + 16777216);  // 128 KB

  // 1) fused prep: coeff+build || hint->fp16 (XCD-aligned) || Wt transpose
  k_prep<<<PREP_A + PREP_B + PREP_C, 256, 0, stream>>>(
      edge_fts, edge_W, edge_b, cfg, cnt, packed, hint, h16, update_W, wt_hi);
  // 2) fused gather-max + MFMA linear update; grid unit-major for XCD sharding
  k_fused<<<BB * MM * (NN / NPB), 256, 0, stream>>>(h16, node_fts, packed,
                                                    wt_hi, update_b, out);
}

// Round 21
// 92.640 us; speedup vs baseline: 1.0469x; 1.0002x over previous
//
#include <hip/hip_runtime.h>

// Problem constants (fixed by the reference setup)
#define BB 2
#define NN 4096
#define EE 65536
#define MM 4
#define HH 256
#define NPB 16     // nodes per block
#define NXCD 8
#define XPAD 264   // xs row stride in fp16 (528B)

typedef float vf4 __attribute__((ext_vector_type(4)));
typedef int vi2 __attribute__((ext_vector_type(2)));
typedef _Float16 vh4 __attribute__((ext_vector_type(4)));
typedef _Float16 f16x8 __attribute__((ext_vector_type(8)));
typedef float f32x4 __attribute__((ext_vector_type(4)));

// ---------------------------------------------------------------------------
// k_prep (grid-partitioned; overlaps three independent HBM streams):
//  part A [0, 2048): per-edge coeff + packed build, 16 edges/wave (16KB of NT
//          loads in flight — r20's 8KB window still paid one HBM latency per
//          8 edges; part A is prep's dominant 134MB stream). Butterfly reduce;
//          lanes 0..15 run 16 edge-tails in parallel.
//          NO cnt reset: exactly 16 adds/node/call -> &15 gives 16 distinct
//          slots from any start; max is permutation-invariant.
//  part B [2048, 10240): hint f32 -> fp16, XCD-aligned, one float4/thread.
//  part C [10240, 10304): W -> Wt fp16 transpose (verified r13)
// ---------------------------------------------------------------------------
#define PREP_A 2048
#define PREP_B 8192
#define PREP_C 64

__global__ __launch_bounds__(256) void k_prep(const float* __restrict__ edge_fts,
                                              const float* __restrict__ edge_W,
                                              const float* __restrict__ edge_b,
                                              const int* __restrict__ cfg,
                                              unsigned int* __restrict__ cnt,
                                              int2* __restrict__ packed,
                                              const float* __restrict__ hint,
                                              _Float16* __restrict__ h16,
                                              const float* __restrict__ W,
                                              _Float16* __restrict__ wt_hi) {
  const int blk = blockIdx.x;
  const int t = threadIdx.x;
  if (blk < PREP_A) {
    // ---- part A: coeff + build, 16 edges per wave ----
    const int e0 = blk * 64 + (t >> 6) * 16;  // first of 16 flat edge indices
    const int lane = t & 63;
    const float4 wv = *reinterpret_cast<const float4*>(edge_W + lane * 4);
    float s[16];
#pragma unroll
    for (int q = 0; q < 16; ++q) {
      const vf4 ef = __builtin_nontemporal_load(
          reinterpret_cast<const vf4*>(edge_fts + (size_t)(e0 + q) * HH + lane * 4));
      s[q] = ef.x * wv.x + ef.y * wv.y + ef.z * wv.z + ef.w * wv.w;
    }
    // butterfly: every lane ends with the full 64-lane sum of each edge
#pragma unroll
    for (int off = 1; off < 64; off <<= 1) {
#pragma unroll
      for (int q = 0; q < 16; ++q) s[q] += __shfl_xor(s[q], off);
    }
    if (lane < 16) {
      // compile-time select chain (no runtime-indexed array -> no scratch)
      float sv = s[15];
#pragma unroll
      for (int q = 14; q >= 0; --q) sv = (lane == q) ? s[q] : sv;
      const int widx = e0 + lane;
      const int b = widx >> 16;  // E = 65536
      const vi2 st = __builtin_nontemporal_load(
          reinterpret_cast<const vi2*>(cfg + (size_t)widx * 2));  // (src, tgt)
      const int slot = b * NN + st.y;
      const unsigned p = atomicAdd(&cnt[slot], 1u) & 15u;
      int2 v;
      v.x = st.x;
      v.y = __float_as_int(sv + edge_b[0]);
      packed[(size_t)slot * 16 + p] = v;
    }
  } else if (blk < PREP_A + PREP_B) {
    // ---- part B: hint -> fp16, XCD-aligned; ONE float4 per thread ----
    const int j = blk - PREP_A;            // 0..8191
    const int unit = j & 7;                // slice (b,m) this XCD owns in k_fused
    const int g = j >> 3;                  // 0..1023: row group (4 rows)
    const int b = unit >> 2;
    const int m = unit & 3;
    const int row = g * 4 + (t >> 6);      // 0..4095
    const int c4 = t & 63;
    const size_t off = (((size_t)(b * NN + row) * MM + m) * HH) + c4 * 4;
    const vf4 v = __builtin_nontemporal_load(
        reinterpret_cast<const vf4*>(hint + off));
    vh4 h;
    h.x = (_Float16)v.x; h.y = (_Float16)v.y;
    h.z = (_Float16)v.z; h.w = (_Float16)v.w;
    *reinterpret_cast<vh4*>(h16 + off) = h;
  } else {
    // ---- part C: Wt transpose (fp16) ----
    const int jb = blk - PREP_A - PREP_B;   // 0..63
    const int j = jb * 4 + (t >> 6);        // output row of Wt = column of W
    const int h0 = (t & 63) * 4;
    vh4 hi;
    hi.x = (_Float16)W[(size_t)(h0 + 0) * HH + j];
    hi.y = (_Float16)W[(size_t)(h0 + 1) * HH + j];
    hi.z = (_Float16)W[(size_t)(h0 + 2) * HH + j];
    hi.w = (_Float16)W[(size_t)(h0 + 3) * HH + j];
    *reinterpret_cast<vh4*>(wt_hi + (size_t)j * HH + h0) = hi;
  }
}

__device__ __forceinline__ float4 fmax4(const float4& a, const float4& b) {
  return make_float4(fmaxf(a.x, b.x), fmaxf(a.y, b.y), fmaxf(a.z, b.z), fmaxf(a.w, b.w));
}

__device__ __forceinline__ float4 scmul(float c, const vh4& h) {
  return make_float4(c * (float)h.x, c * (float)h.y, c * (float)h.z, c * (float)h.w);
}

// ---------------------------------------------------------------------------
// k_fused (XCD-sharded, fp16 gather + MFMA GEMM).
// r21: stage-2 ct loop unroll 2 — two independent acc chains, ~16 Wt loads
// in flight across ct pairs (r20's `unroll 1` serialized ct iterations:
// each ct's 8 loads fully drained before the next issued).
// ---------------------------------------------------------------------------
__global__ __launch_bounds__(256, 6) void k_fused(const _Float16* __restrict__ h16,
                                                  const float* __restrict__ node_fts,
                                                  const int2* __restrict__ packed,
                                                  const _Float16* __restrict__ wt_hi,
                                                  const float* __restrict__ bias,
                                                  float* __restrict__ out) {
  __shared__ _Float16 xs[NPB][XPAD];   // 8.4 KB
  __shared__ int ssrc[NPB][16];        // 1 KB
  __shared__ float scf[NPB][16];       // 1 KB

  const int t = threadIdx.x;
  const int unit = blockIdx.x & (NXCD - 1);   // = b*4 + m  (XCD-pinned slice)
  const int chunk = blockIdx.x >> 3;
  const int b = unit >> 2;
  const int m = unit & 3;
  const int n0 = chunk * NPB;
  const int w = t >> 6;
  const int lane = t & 63;
  const int r0 = w * 4;     // this wave's first local row

  // ---- stage 0 (intra-wave): thread t stages (row t>>4, slot t&15) ----
  {
    const int i = t >> 4, k = t & 15;   // i in [4w, 4w+3] for this wave
    const int2 v = packed[(size_t)(b * NN + n0 + i) * 16 + k];
    ssrc[i][k] = v.x;
    scf[i][k] = __int_as_float(v.y);
  }

  // per-thread base into h16 for (b, m, lane)
  const _Float16* hb = h16 + (size_t)b * NN * MM * HH + m * HH + lane * 4;

  // ---- stage 1: fp16 gather + scale + tree-max + node_fts -> xs (own rows) ----
#pragma unroll 1
  for (int i = 0; i < 4; ++i) {
    const int lr = r0 + i;
    const int n = n0 + lr;
    vh4 hv[16];
#pragma unroll
    for (int k = 0; k < 16; ++k) {
      const int s = ssrc[lr][k];
      hv[k] = *reinterpret_cast<const vh4*>(hb + (size_t)s * (MM * HH));
    }
    float4 t8[8];
#pragma unroll
    for (int k = 0; k < 8; ++k)
      t8[k] = fmax4(scmul(scf[lr][2 * k], hv[2 * k]),
                    scmul(scf[lr][2 * k + 1], hv[2 * k + 1]));
#pragma unroll
    for (int k = 0; k < 4; ++k) t8[k] = fmax4(t8[k], t8[k + 4]);
    t8[0] = fmax4(t8[0], t8[2]);
    t8[1] = fmax4(t8[1], t8[3]);
    const float4 a = fmax4(t8[0], t8[1]);
    const vf4 nf = __builtin_nontemporal_load(reinterpret_cast<const vf4*>(
        node_fts + (((size_t)(b * NN + n) * MM + m) * HH) + lane * 4));
    vh4 xq;
    xq.x = (_Float16)(nf.x + a.x);
    xq.y = (_Float16)(nf.y + a.y);
    xq.z = (_Float16)(nf.z + a.z);
    xq.w = (_Float16)(nf.w + a.w);
    *reinterpret_cast<vh4*>(&xs[lr][lane * 4]) = xq;
  }
  __syncthreads();  // stage 2 reads rows produced by all waves

  // ---- stage 2: MFMA GEMM [16x256] = xs[16x256] @ W[256x256] ----
  const int lr16 = lane & 15;
  const int kg = lane >> 4;         // 0..3: k-subgroup (8 consecutive k)

#pragma unroll 2
  for (int ct = 0; ct < 4; ++ct) {
    const int j = (w * 4 + ct) * 16 + lr16;
    const _Float16* bh = wt_hi + (size_t)j * HH + kg * 8;
    f32x4 acc = {0.f, 0.f, 0.f, 0.f};
#pragma unroll
    for (int kt = 0; kt < 8; ++kt) {
      const f16x8 bhi = *reinterpret_cast<const f16x8*>(bh + kt * 32);
      const f16x8 a = *reinterpret_cast<const f16x8*>(&xs[lr16][kt * 32 + kg * 8]);
      acc = __builtin_amdgcn_mfma_f32_16x16x32_f16(a, bhi, acc, 0, 0, 0);
    }
    const float bj = bias[j];
#pragma unroll
    for (int r = 0; r < 4; ++r) {
      const int n = n0 + kg * 4 + r;
      __builtin_nontemporal_store(
          acc[r] + bj, out + (((size_t)(b * NN + n) * MM + m) * HH) + j);
    }
  }
}

// ---------------------------------------------------------------------------
extern "C" void kernel_launch(void* const* d_in, const int* in_sizes, int n_in,
                              void* d_out, int out_size, void* d_ws, size_t ws_size,
                              hipStream_t stream) {
  const int* cfg = (const int*)d_in[0];          // [B,E,2]
  const float* hint = (const float*)d_in[1];     // [B,N,M,H]
  const float* node_fts = (const float*)d_in[2]; // [B,N,M,H]
  const float* edge_fts = (const float*)d_in[3]; // [B,E,H]
  const float* edge_W = (const float*)d_in[4];   // [H,1]
  const float* edge_b = (const float*)d_in[5];   // [1]
  const float* update_W = (const float*)d_in[6]; // [H,H]
  const float* update_b = (const float*)d_in[7]; // [H]
  float* out = (float*)d_out;

  char* ws = (char*)d_ws;
  unsigned int* cnt = (unsigned int*)ws;                         // 32 KB (never reset)
  int2* packed = (int2*)(ws + 32768);                            // B*N*16 int2 = 1 MB
  _Float16* h16 = (_Float16*)(ws + 32768 + 1048576);             // 16.78 MB
  _Float16* wt_hi = (_Float16*)(ws + 32768 + 1048576 + 16777216);  // 128 KB

  // 1) fused prep: coeff+build || hint->fp16 (XCD-aligned) || Wt transpose
  k_prep<<<PREP_A + PREP_B + PREP_C, 256, 0, stream>>>(
      edge_fts, edge_W, edge_b, cfg, cnt, packed, hint, h16, update_W, wt_hi);
  // 2) fused gather-max + MFMA linear update; grid unit-major for XCD sharding
  k_fused<<<BB * MM * (NN / NPB), 256, 0, stream>>>(h16, node_fts, packed,
                                                    wt_hi, update_b, out);
}